// Round 2
// baseline (3629.924 us; speedup 1.0000x reference)
//
#include <hip/hip_runtime.h>

// GAT encoder, B=8, N=1024, D=768, H=4. adj int32; float tensors bf16 OR f32,
// runtime-detected (flag in ws). Outputs: yy [B,N,D] then node_scores [B,N].
//
// DIRECT-FRAG ROUND: mgemm rewritten as 1-wave-per-block, LDS-free GEMM.
// Each wave computes a 32x64 C-tile (2x4 frags of 16x16x32 f16 MFMA), loading
// A- and B-fragments straight from global (L2-resident operands) with a
// 4-stage depth-2 software pipeline. No barriers, no LDS, 384 blocks/GEMM
// (vs 192 4-wave blocks before -> ~1 wave/SIMD with nothing to overlap).
// Fragment lane mapping identical to the round-1 kernel that passed:
//   A/B: row|col = lane&15, k = 8*(lane>>4)+j;  C: col=lane&15, row=4*(lane>>4)+r.
//
// ws (peak 6,824,192 B, unchanged):
//   f1 f32[1024] @0, f2 @4096, flag @8192,
//   Wh1T f16[768,1024] @8448, Wh2T @1581312, att f16[1024,1024] @3154176,
//   WT f16[768,768] ALIASES att (live only T1->G1 and T2->G3),
//   hout f16[1024,768] @5251328 (end 6,824,192).

typedef unsigned short ushortT;
typedef _Float16 f16;
typedef __attribute__((ext_vector_type(8))) _Float16 f16x8;
typedef __attribute__((ext_vector_type(4))) _Float16 f16x4;
typedef __attribute__((ext_vector_type(4))) float f32x4;
typedef __attribute__((ext_vector_type(8))) unsigned short u16x8;

#define ALPHA 0.2f

__device__ __forceinline__ float b2f(ushortT u) {
  union { unsigned int i; float f; } c; c.i = ((unsigned int)u) << 16; return c.f;
}
__device__ __forceinline__ ushortT f2b(float f) {
  union { float f; unsigned int u; } c; c.f = f;
  unsigned int u = c.u;
  u += 0x7FFFu + ((u >> 16) & 1u);   // RNE
  return (ushortT)(u >> 16);
}

// ---- dtype detector: low 16-bit halves of f32 words are mantissa noise -------
__global__ void detect_dtype(const ushortT* __restrict__ X, int* __restrict__ flag) {
  __shared__ int s[256];
  int t = threadIdx.x, c = 0;
  for (int i = t; i < 16384; i += 256) {
    int e = (X[2 * i] >> 7) & 0xFF;
    if (e > 140 || e < 100) c++;     // genuine bf16 N(0,1): essentially never
  }
  s[t] = c; __syncthreads();
  for (int o = 128; o > 0; o >>= 1) { if (t < o) s[t] += s[t + o]; __syncthreads(); }
  if (t == 0) *flag = (s[0] > 1000) ? 1 : 0;   // 1 -> inputs are f32
}

// ---- 768x768 weight transpose: WT[c][r] = W[wOff + r*768 + c], f16 out -------
__global__ __launch_bounds__(256) void transpose_w(
    const void* __restrict__ W, f16* __restrict__ WT, long wOff,
    const int* __restrict__ rflag) {
  __shared__ float tile[32][33];
  int flg = *rflag;
  int tx = threadIdx.x & 31, ty = threadIdx.x >> 5;
  int c0 = blockIdx.x * 32, r0 = blockIdx.y * 32;
  const float* Wf = (const float*)W; const ushortT* Wu = (const ushortT*)W;
#pragma unroll
  for (int i = 0; i < 4; i++) {
    int r = r0 + ty + i * 8;
    long gi = wOff + (long)r * 768 + c0 + tx;
    tile[ty + i * 8][tx] = flg ? Wf[gi] : b2f(Wu[gi]);
  }
  __syncthreads();
#pragma unroll
  for (int i = 0; i < 4; i++) {
    int c = c0 + ty + i * 8;
    WT[(long)c * 768 + r0 + tx] = (f16)tile[tx][ty + i * 8];
  }
}

// ---- MFMA GEMM, 1 wave/block, no LDS: C[1024,768] = A[1024,K] @ B[K,768] ----
// BT is [768][K] f16 (row stride K). ARAW: 0 -> A is f16; 1 -> A raw input
// (bf16 or f32 per *rflag), converted at consume time.
// MODE 1: elu, f16, normal layout (hout). MODE 2: elu + residual(raw), store
// flag dtype at cOff (final yy). MODE 3: f16 accumulate, TRANSPOSED store
// (Wh2T). MODE 4: f16 plain TRANSPOSED store (Wh1T).
// Wave tile 32x64: Ma=2 (m0+0..15, +16..31), Nb=4 (n0+16*fn). Grid (12,32).
// 4-stage modulo pipeline, loads issued 2 stages ahead (KT in {24,32}, %4==0).
template <int MODE, int ARAW>
__global__ __launch_bounds__(64) void mgemm(
    const void* __restrict__ Ab, const f16* __restrict__ BT,
    void* __restrict__ Cb, const void* __restrict__ Rb,
    int K, int lda,
    long aOff, long cOff, long rOff, int accum,
    const int* __restrict__ rflag) {
  int l = threadIdx.x;               // 0..63, one wave
  int lr = l & 15, lg = l >> 4;
  int n0 = blockIdx.x * 64, m0 = blockIdx.y * 32;
  int flg = *rflag;
  int aTy = ARAW ? (flg ? 2 : 1) : 0;   // 0 f16, 1 bf16, 2 f32

  const f16*     Ah = (const f16*)Ab;
  const ushortT* Au = (const ushortT*)Ab;
  const float*   Af = (const float*)Ab;

  // per-lane element bases (A: frag rows lr and lr+16; B: frag cols lr+16*fn)
  long aRow0 = aOff + (long)(m0 + lr) * lda + lg * 8;
  long aRow1 = aRow0 + 16L * lda;
  long bCol  = (long)(n0 + lr) * (long)K + lg * 8;
  long bStep = 16L * K;

  f32x4 acc00 = {0,0,0,0}, acc01 = {0,0,0,0}, acc02 = {0,0,0,0}, acc03 = {0,0,0,0};
  f32x4 acc10 = {0,0,0,0}, acc11 = {0,0,0,0}, acc12 = {0,0,0,0}, acc13 = {0,0,0,0};

  // stage load: raw 16B payload for A (f16/bf16) or 2x16B (f32), B always f16
  auto LD = [&](f32x4& a0l, f32x4& a0h, f32x4& a1l, f32x4& a1h,
                f16x8& b0, f16x8& b1, f16x8& b2, f16x8& b3, int kt) {
    long ka = (long)kt * 32;
    if (aTy == 2) {
      a0l = *(const f32x4*)(Af + aRow0 + ka); a0h = *(const f32x4*)(Af + aRow0 + ka + 4);
      a1l = *(const f32x4*)(Af + aRow1 + ka); a1h = *(const f32x4*)(Af + aRow1 + ka + 4);
    } else if (aTy == 1) {
      a0l = *(const f32x4*)(Au + aRow0 + ka);
      a1l = *(const f32x4*)(Au + aRow1 + ka);
    } else {
      a0l = *(const f32x4*)(Ah + aRow0 + ka);
      a1l = *(const f32x4*)(Ah + aRow1 + ka);
    }
    b0 = *(const f16x8*)(BT + bCol + ka);
    b1 = *(const f16x8*)(BT + bCol + bStep + ka);
    b2 = *(const f16x8*)(BT + bCol + 2 * bStep + ka);
    b3 = *(const f16x8*)(BT + bCol + 3 * bStep + ka);
  };
  auto CVT = [&](f32x4 lo, f32x4 hi) -> f16x8 {
    f16x8 r;
    if (aTy == 0) {
      r = __builtin_bit_cast(f16x8, lo);
    } else if (aTy == 1) {
      u16x8 u = __builtin_bit_cast(u16x8, lo);
#pragma unroll
      for (int j = 0; j < 8; j++) r[j] = (f16)b2f(u[j]);
    } else {
#pragma unroll
      for (int j = 0; j < 4; j++) { r[j] = (f16)lo[j]; r[4 + j] = (f16)hi[j]; }
    }
    return r;
  };
  auto CP = [&](f32x4 a0l, f32x4 a0h, f32x4 a1l, f32x4 a1h,
                f16x8 b0, f16x8 b1, f16x8 b2, f16x8 b3) {
    f16x8 a0 = CVT(a0l, a0h), a1 = CVT(a1l, a1h);
    acc00 = __builtin_amdgcn_mfma_f32_16x16x32_f16(a0, b0, acc00, 0, 0, 0);
    acc01 = __builtin_amdgcn_mfma_f32_16x16x32_f16(a0, b1, acc01, 0, 0, 0);
    acc02 = __builtin_amdgcn_mfma_f32_16x16x32_f16(a0, b2, acc02, 0, 0, 0);
    acc03 = __builtin_amdgcn_mfma_f32_16x16x32_f16(a0, b3, acc03, 0, 0, 0);
    acc10 = __builtin_amdgcn_mfma_f32_16x16x32_f16(a1, b0, acc10, 0, 0, 0);
    acc11 = __builtin_amdgcn_mfma_f32_16x16x32_f16(a1, b1, acc11, 0, 0, 0);
    acc12 = __builtin_amdgcn_mfma_f32_16x16x32_f16(a1, b2, acc12, 0, 0, 0);
    acc13 = __builtin_amdgcn_mfma_f32_16x16x32_f16(a1, b3, acc13, 0, 0, 0);
  };

#define STG(S) f32x4 S##a0l, S##a0h, S##a1l, S##a1h; f16x8 S##b0, S##b1, S##b2, S##b3;
  STG(s0) STG(s1) STG(s2) STG(s3)
#define LOAD(S, kt) LD(S##a0l, S##a0h, S##a1l, S##a1h, S##b0, S##b1, S##b2, S##b3, kt)
#define COMP(S)     CP(S##a0l, S##a0h, S##a1l, S##a1h, S##b0, S##b1, S##b2, S##b3)

  int KT = K >> 5;                   // 24 or 32; both %4 == 0
  LOAD(s0, 0); LOAD(s1, 1);
  for (int kt = 0; kt + 4 <= KT; kt += 4) {
    LOAD(s2, kt + 2); COMP(s0);
    LOAD(s3, kt + 3); COMP(s1);
    if (kt + 4 < KT) LOAD(s0, kt + 4);
    COMP(s2);
    if (kt + 5 < KT) LOAD(s1, kt + 5);
    COMP(s3);
  }
#undef STG
#undef LOAD
#undef COMP

  // epilogue: C frag mapping col = lane&15, row = 4*(lane>>4)+reg
  int rowb_base = m0 + 4 * lg;
  int col_base  = n0 + lr;
  f32x4 accv[2][4] = {{acc00, acc01, acc02, acc03}, {acc10, acc11, acc12, acc13}};
#pragma unroll
  for (int fm = 0; fm < 2; fm++) {
#pragma unroll
    for (int fn = 0; fn < 4; fn++) {
      int rowb = rowb_base + fm * 16;
      int col  = col_base + fn * 16;
      f32x4 v = accv[fm][fn];
      if (MODE == 4) {                       // transposed plain store (Wh1T)
        f16x4 pk;
#pragma unroll
        for (int r = 0; r < 4; r++) pk[r] = (f16)v[r];
        *(f16x4*)((f16*)Cb + (long)col * 1024 + rowb) = pk;
      } else if (MODE == 3) {                // transposed accumulate (Wh2T)
        f16* Cc = (f16*)Cb;
        long idx = (long)col * 1024 + rowb;
        f16x4 pk;
        if (accum) {
          f16x4 old = *(const f16x4*)(Cc + idx);
#pragma unroll
          for (int r = 0; r < 4; r++) pk[r] = (f16)((float)old[r] + v[r]);
        } else {
#pragma unroll
          for (int r = 0; r < 4; r++) pk[r] = (f16)v[r];
        }
        *(f16x4*)(Cc + idx) = pk;
      } else {
#pragma unroll
        for (int r = 0; r < 4; r++) {
          int row = rowb + r;
          float x = v[r];
          x = x > 0.f ? x : expm1f(x);       // elu (MODE 1 and 2)
          long ci = cOff + (long)row * 768 + col;
          if (MODE == 2) {
            long ri = rOff + (long)row * 768 + col;
            x += flg ? ((const float*)Rb)[ri] : b2f(((const ushortT*)Rb)[ri]);
            if (flg) ((float*)Cb)[ci] = x;
            else     ((ushortT*)Cb)[ci] = f2b(x);
          } else {
            ((f16*)Cb)[ci] = (f16)x;
          }
        }
      }
    }
  }
}

// ---- f1/f2 dots on TRANSPOSED Wh (WhT [768][1024] f16): coalesced on nodes --
__global__ __launch_bounds__(256) void fdotT_kernel(
    const f16* __restrict__ WhT, const void* __restrict__ avec, long aOff,
    float* __restrict__ f1, float* __restrict__ f2, const int* __restrict__ rflag) {
  __shared__ float s1m[8][32], s2m[8][32];
  int t = threadIdx.x, n = t & 31, fl = t >> 5;
  int node = blockIdx.x * 32 + n;
  int flg = *rflag;
  const float* af = (const float*)avec; const ushortT* au = (const ushortT*)avec;
  float s1 = 0.f, s2 = 0.f;
  for (int f = fl; f < 768; f += 8) {
    float wv = (float)WhT[(long)f * 1024 + node];
    float a1 = flg ? af[aOff + f]       : b2f(au[aOff + f]);
    float a2 = flg ? af[aOff + 768 + f] : b2f(au[aOff + 768 + f]);
    s1 += wv * a1; s2 += wv * a2;
  }
  s1m[fl][n] = s1; s2m[fl][n] = s2;
  __syncthreads();
  if (t < 32) {
    float r1 = 0.f, r2 = 0.f;
#pragma unroll
    for (int j = 0; j < 8; j++) { r1 += s1m[j][t]; r2 += s2m[j][t]; }
    f1[blockIdx.x * 32 + t] = r1;
    f2[blockIdx.x * 32 + t] = r2;
  }
}

// ---- masked row softmax over 1024 cols; one block per row i; f16 out ---------
__global__ __launch_bounds__(256) void attn_kernel(
    const float* __restrict__ f1, const float* __restrict__ f2,
    const int* __restrict__ adj, f16* __restrict__ att) {
  __shared__ float sred[8];
  int i = blockIdx.x;
  const int* arow = adj + (size_t)i * 1024;
  float f1i = f1[i];
  f16* orow = att + (size_t)i * 1024;
  int t = threadIdx.x, lane = t & 63, wid = t >> 6;

  float e[4];
  int msk[4];
  float mx = -1e38f;
#pragma unroll
  for (int c = 0; c < 4; c++) {
    int j = t + c * 256;
    float ev = f1i + f2[j];
    ev = ev > 0.f ? ev : ALPHA * ev;
    e[c] = ev;
    msk[c] = arow[j] > 0;
    if (msk[c]) mx = fmaxf(mx, ev);
  }
#pragma unroll
  for (int o = 32; o > 0; o >>= 1) mx = fmaxf(mx, __shfl_down(mx, o));
  if (lane == 0) sred[wid] = mx;
  __syncthreads();
  float bmx = fmaxf(fmaxf(sred[0], sred[1]), fmaxf(sred[2], sred[3]));
  bool none = bmx < -1e37f;   // all-masked row -> reference softmax is uniform

  float p[4];
  float sum = 0.f;
#pragma unroll
  for (int c = 0; c < 4; c++) {
    p[c] = none ? 1.f : (msk[c] ? expf(e[c] - bmx) : 0.f);
    sum += p[c];
  }
#pragma unroll
  for (int o = 32; o > 0; o >>= 1) sum += __shfl_down(sum, o);
  if (lane == 0) sred[4 + wid] = sum;
  __syncthreads();
  float inv = 1.f / (sred[4] + sred[5] + sred[6] + sred[7]);
#pragma unroll
  for (int c = 0; c < 4; c++) orow[t + c * 256] = (f16)(p[c] * inv);
}

// ---- classifier: scores[row] = sigmoid(yy[row]@w + b) * mask[row] ------------
__global__ __launch_bounds__(256) void cls_kernel(
    void* __restrict__ outbase, const void* __restrict__ w,
    const void* __restrict__ bc, const void* __restrict__ mask,
    const int* __restrict__ rflag) {
  int t = threadIdx.x, lane = t & 63, wv = t >> 6;
  long row = (long)blockIdx.x * 4 + wv;    // 0..8191
  int f32 = *rflag;
  const float* yf = (const float*)outbase; const ushortT* yu = (const ushortT*)outbase;
  const float* wf = (const float*)w;       const ushortT* wu = (const ushortT*)w;
  float s = 0.f;
  for (int d = lane; d < 768; d += 64) {
    float yv = f32 ? yf[row * 768 + d] : b2f(yu[row * 768 + d]);
    float wvv = f32 ? wf[d] : b2f(wu[d]);
    s += yv * wvv;
  }
#pragma unroll
  for (int o = 32; o > 0; o >>= 1) s += __shfl_down(s, o);
  if (lane == 0) {
    float bb = f32 ? ((const float*)bc)[0] : b2f(((const ushortT*)bc)[0]);
    float mk = f32 ? ((const float*)mask)[row] : b2f(((const ushortT*)mask)[row]);
    float sig = 1.f / (1.f + expf(-(s + bb)));
    long oi = 6291456L + row;
    if (f32) ((float*)outbase)[oi] = sig * mk;
    else ((ushortT*)outbase)[oi] = f2b(sig * mk);
  }
}

extern "C" void kernel_launch(void* const* d_in, const int* in_sizes, int n_in,
                              void* d_out, int out_size, void* d_ws, size_t ws_size,
                              hipStream_t stream) {
  (void)in_sizes; (void)n_in; (void)out_size; (void)ws_size;

  const void* X    = d_in[0];               // [8,1024,768]
  const int*  adj  = (const int*)d_in[1];   // [8,1024,1024]
  const void* maskN= d_in[2];               // [8,1024]
  const void* Wh   = d_in[3];               // [4,768,768]
  const void* aH   = d_in[4];               // [4,1536]
  const void* Wo   = d_in[5];               // [3072,768]
  const void* aO   = d_in[6];               // [1536]
  const void* wcls = d_in[7];               // [768]
  const void* bcls = d_in[8];               // [1]

  char* ws = (char*)d_ws;
  float* f1   = (float*)(ws + 0);           // [1024]
  float* f2   = (float*)(ws + 4096);        // [1024]
  int*   flag = (int*)(ws + 8192);
  f16* Wh1T = (f16*)(ws + 8448);            // [768,1024] f16
  f16* Wh2T = (f16*)(ws + 1581312);         // [768,1024] f16
  f16* attb = (f16*)(ws + 3154176);         // [1024,1024] f16
  f16* WT   = (f16*)(ws + 3154176);         // [768,768] f16, ALIASES attb
  f16* hout = (f16*)(ws + 5251328);         // [1024,768] f16; end 6,824,192

  detect_dtype<<<1, 256, 0, stream>>>((const ushortT*)X, flag);

  dim3 gg(12, 32);     // N tiles (64) x M tiles (32), 1 wave per block
  dim3 tg(24, 24);     // 32x32 transpose tiles
  for (int b = 0; b < 8; b++) {
    long xOff = (long)b * 786432;
    for (int h = 0; h < 4; h++) {
      // T1: WT = W_heads[h]^T (f16)
      transpose_w<<<tg, 256, 0, stream>>>(Wh, WT, (long)h * 589824, flag);
      // G1: Wh1T = (X[b] @ W_heads[h])^T
      mgemm<4, 1><<<gg, 64, 0, stream>>>(X, WT, Wh1T, nullptr,
                                         768, 768, xOff, 0L, 0L, 0, flag);
      // F1
      fdotT_kernel<<<32, 256, 0, stream>>>(Wh1T, aH, (long)h * 1536, f1, f2, flag);
      // A1
      attn_kernel<<<1024, 256, 0, stream>>>(f1, f2, adj + (size_t)b * 1048576, attb);
      // G2: hout = elu(att @ Wh1)
      mgemm<1, 0><<<gg, 64, 0, stream>>>(attb, Wh1T, hout, nullptr,
                                         1024, 1024, 0L, 0L, 0L, 0, flag);
      // T2: WT = W_out[h*768:(h+1)*768, :]^T  (att consumed by G2 -> safe)
      transpose_w<<<tg, 256, 0, stream>>>(Wo, WT, (long)h * 589824, flag);
      // G3: Wh2T (+)= (hout @ Wo_slice)^T
      mgemm<3, 0><<<gg, 64, 0, stream>>>(hout, WT, Wh2T, nullptr,
                                         768, 768, 0L, 0L, 0L, h > 0 ? 1 : 0, flag);
    }
    // F2 / A2 on layer-2 features
    fdotT_kernel<<<32, 256, 0, stream>>>(Wh2T, aO, 0L, f1, f2, flag);
    attn_kernel<<<1024, 256, 0, stream>>>(f1, f2, adj + (size_t)b * 1048576, attb);
    // G4: yy[b] = elu(att2 @ Wh2) + X[b]  -> d_out (flag dtype)
    mgemm<2, 0><<<gg, 64, 0, stream>>>(attb, Wh2T, d_out, X,
                                       1024, 1024, 0L, xOff, xOff, 0, flag);
  }

  cls_kernel<<<2048, 256, 0, stream>>>(d_out, wcls, bcls, maskN, flag);
}

// Round 3
// 1965.705 us; speedup vs baseline: 1.8466x; 1.8466x over previous
//
#include <hip/hip_runtime.h>

// GAT encoder, B=8, N=1024, D=768, H=4. adj int32; float tensors bf16 OR f32,
// runtime-detected (flag in ws). Outputs: yy [B,N,D] then node_scores [B,N].
//
// FUSION ROUND (revert of round-2's direct-frag regression; base = round-1 LDS
// mgemm at 3106 us):
//  * BSRC=1 staging: mgemm transposes raw row-major W/Wo into the swizzled
//    Bs[n][k] LDS tile itself (coalesced k-row loads) -> transpose_w kernels
//    (64 dispatches) and the WT buffer are GONE.
//  * fdot fused into G1 epilogue and the h=3 G3 epilogue: per-lane partials of
//    Wh@a1 / Wh@a2, shfl_xor-reduced over the 16 col-lanes, atomicAdd into
//    f1/f2 (pre-zeroed by a hipMemsetAsync node). fdotT kernels (40) GONE.
//  * attn_kernel loads vectorized (int4/float4/f16x4).
// Dispatches: 250 -> 186.
//
// ws (peak 6,824,192 B, unchanged):
//   f1 f32[1024] @0, f2 @4096, flag @8192,
//   Wh1T f16[768,1024] @8448, Wh2T @1581312, att f16[1024,1024] @3154176,
//   hout f16[1024,768] @5251328 (end 6,824,192).

typedef unsigned short ushortT;
typedef _Float16 f16;
typedef __attribute__((ext_vector_type(8))) _Float16 f16x8;
typedef __attribute__((ext_vector_type(4))) _Float16 f16x4;
typedef __attribute__((ext_vector_type(4))) float f32x4;
typedef __attribute__((ext_vector_type(2))) float f32x2;
typedef __attribute__((ext_vector_type(8))) unsigned short u16x8;
typedef __attribute__((ext_vector_type(2))) unsigned short u16x2;
typedef __attribute__((ext_vector_type(4))) int i32x4;

#define ALPHA 0.2f

__device__ __forceinline__ float b2f(ushortT u) {
  union { unsigned int i; float f; } c; c.i = ((unsigned int)u) << 16; return c.f;
}
__device__ __forceinline__ ushortT f2b(float f) {
  union { float f; unsigned int u; } c; c.f = f;
  unsigned int u = c.u;
  u += 0x7FFFu + ((u >> 16) & 1u);   // RNE
  return (ushortT)(u >> 16);
}

// ---- dtype detector: low 16-bit halves of f32 words are mantissa noise -------
__global__ void detect_dtype(const ushortT* __restrict__ X, int* __restrict__ flag) {
  __shared__ int s[256];
  int t = threadIdx.x, c = 0;
  for (int i = t; i < 16384; i += 256) {
    int e = (X[2 * i] >> 7) & 0xFF;
    if (e > 140 || e < 100) c++;     // genuine bf16 N(0,1): essentially never
  }
  s[t] = c; __syncthreads();
  for (int o = 128; o > 0; o >>= 1) { if (t < o) s[t] += s[t + o]; __syncthreads(); }
  if (t == 0) *flag = (s[0] > 1000) ? 1 : 0;   // 1 -> inputs are f32
}

// ---- MFMA GEMM: C[1024,768] = A[1024,K] @ B[K,768] --------------------------
// BSRC 0: Bb is BT f16 [768][K] (row stride K), staged with 16B loads.
// BSRC 1: Bb is raw row-major [K][768] (f32/bf16 per flag), transposed into the
//         same swizzled Bs[n][k] layout during staging (coalesced k-row loads).
// aRaw: 1 -> A raw (f32/bf16 per flag), 0 -> f16.
// MODE 1: elu -> f16 (hout). MODE 2: elu + residual(raw) -> flag dtype (yy).
// MODE 3: f16 accumulate, TRANSPOSED store (Wh2T). MODE 4: f16 plain
// TRANSPOSED store (Wh1T).
// fd != 0: fused fdot epilogue: f1[row] += sum_col C[row][col]*a1[col], f2 w/ a2
//          (avec raw dtype at avOff; fvec = f1 base, f2 = fvec+1024; pre-zeroed).
// Block 256 = 4 waves (2x2 of 32x32), tile BM=64 BN=64 BK=64, grid (12,16).
template <int MODE, int BSRC>
__global__ __launch_bounds__(256) void mgemm(
    const void* __restrict__ Ab, const void* __restrict__ Bb,
    void* __restrict__ Cb, const void* __restrict__ Rb,
    int K, int lda, int ldb, int aRaw,
    long aOff, long bOff, long cOff, long rOff, int accum,
    const void* __restrict__ avec, long avOff, int fd, float* __restrict__ fvec,
    const int* __restrict__ rflag) {
  __shared__ __align__(16) f16 As[64 * 64];
  __shared__ __align__(16) f16 Bs[64 * 64];
  int t = threadIdx.x;
  int n0 = blockIdx.x * 64, m0 = blockIdx.y * 64;
  int flg = *rflag;
  int aTy = aRaw ? (flg ? 2 : 1) : 0;   // 0 f16, 1 bf16, 2 f32

  // A staging: thread t owns tile row tq, 16-elem k-group cq (2 chunks of 8)
  int tq = t >> 2, cq = t & 3;
  long aBase = aOff + (long)(m0 + tq) * lda + cq * 16;
  int stA0 = tq * 64 + (((2 * cq)     ^ (tq & 7)) * 8);
  int stA1 = tq * 64 + (((2 * cq + 1) ^ (tq & 7)) * 8);

  const f16*     Ah = (const f16*)Ab;
  const ushortT* Au = (const ushortT*)Ab;
  const float*   Af = (const float*)Ab;
  const f16*     Bh = (const f16*)Bb;
  const ushortT* Bu = (const ushortT*)Bb;
  const float*   Bf = (const float*)Bb;

  // B staging geometry
  long bBase = 0;
  int stB0, stB1;
  int q2 = 0, cB = 0;
  if (BSRC == 0) {
    bBase = bOff + (long)(n0 + tq) * (long)K + cq * 16;
    stB0 = stA0; stB1 = stA1;
  } else {
    q2 = t & 31; cB = t >> 5;                 // n-pair 2*q2, chunk cB (0..7)
    int nb0 = 2 * q2, nb1 = nb0 + 1;
    stB0 = nb0 * 64 + ((cB ^ (nb0 & 7)) * 8);
    stB1 = nb1 * 64 + ((cB ^ (nb1 & 7)) * 8);
  }

  f16x8 ra0, ra1, rb0, rb1;   // prefetch regs

  auto loadA = [&](int kt) {
    long g = aBase + (long)kt * 64;
    if (aTy == 0) {
      ra0 = *(const f16x8*)(Ah + g);
      ra1 = *(const f16x8*)(Ah + g + 8);
    } else if (aTy == 1) {
      u16x8 v0 = *(const u16x8*)(Au + g);
      u16x8 v1 = *(const u16x8*)(Au + g + 8);
#pragma unroll
      for (int j = 0; j < 8; j++) { ra0[j] = (f16)b2f(v0[j]); ra1[j] = (f16)b2f(v1[j]); }
    } else {
      f32x4 v0 = *(const f32x4*)(Af + g);
      f32x4 v1 = *(const f32x4*)(Af + g + 4);
      f32x4 v2 = *(const f32x4*)(Af + g + 8);
      f32x4 v3 = *(const f32x4*)(Af + g + 12);
#pragma unroll
      for (int j = 0; j < 4; j++) {
        ra0[j] = (f16)v0[j]; ra0[4 + j] = (f16)v1[j];
        ra1[j] = (f16)v2[j]; ra1[4 + j] = (f16)v3[j];
      }
    }
  };
  auto loadB = [&](int kt) {
    if (BSRC == 0) {
      long g = bBase + (long)kt * 64;
      rb0 = *(const f16x8*)(Bh + g);
      rb1 = *(const f16x8*)(Bh + g + 8);
    } else {
      // raw row-major: rows k = kt*64 + cB*8 + j, cols n0 + 2*q2 (+1)
      long rbase = bOff + (long)(kt * 64 + cB * 8) * ldb + n0 + 2 * q2;
      if (flg) {
#pragma unroll
        for (int j = 0; j < 8; j++) {
          f32x2 v = *(const f32x2*)(Bf + rbase + (long)j * ldb);
          rb0[j] = (f16)v[0]; rb1[j] = (f16)v[1];
        }
      } else {
#pragma unroll
        for (int j = 0; j < 8; j++) {
          u16x2 v = *(const u16x2*)(Bu + rbase + (long)j * ldb);
          rb0[j] = (f16)b2f(v[0]); rb1[j] = (f16)b2f(v[1]);
        }
      }
    }
  };

  // compute-side lane geometry
  int lane = t & 63, wid = t >> 6;
  int wr = wid >> 1, wc = wid & 1;            // 2x2 waves of 32x32
  int lr = lane & 15, lg = lane >> 4, l7 = lane & 7;
  int aRow0 = (wr * 32 + lr) * 64, aRow1 = aRow0 + 16 * 64;
  int bRow0 = (wc * 32 + lr) * 64, bRow1 = bRow0 + 16 * 64;

  f32x4 acc[2][2];
#pragma unroll
  for (int i = 0; i < 2; i++)
#pragma unroll
    for (int j = 0; j < 2; j++) acc[i][j] = (f32x4){0.f, 0.f, 0.f, 0.f};

  int KT = K >> 6;
  loadA(0); loadB(0);
  for (int kt = 0; kt < KT; ++kt) {
    __syncthreads();   // previous tile's LDS readers done
    *(f16x8*)(As + stA0) = ra0;  *(f16x8*)(As + stA1) = ra1;
    *(f16x8*)(Bs + stB0) = rb0;  *(f16x8*)(Bs + stB1) = rb1;
    __syncthreads();
    if (kt + 1 < KT) { loadA(kt + 1); loadB(kt + 1); }  // overlap with MFMAs
#pragma unroll
    for (int kk = 0; kk < 2; kk++) {
      int ch = ((kk * 4 + lg) ^ l7) * 8;   // swizzled 16B chunk
      f16x8 a0 = *(const f16x8*)(As + aRow0 + ch);
      f16x8 a1 = *(const f16x8*)(As + aRow1 + ch);
      f16x8 b0 = *(const f16x8*)(Bs + bRow0 + ch);
      f16x8 b1 = *(const f16x8*)(Bs + bRow1 + ch);
      acc[0][0] = __builtin_amdgcn_mfma_f32_16x16x32_f16(a0, b0, acc[0][0], 0, 0, 0);
      acc[0][1] = __builtin_amdgcn_mfma_f32_16x16x32_f16(a0, b1, acc[0][1], 0, 0, 0);
      acc[1][0] = __builtin_amdgcn_mfma_f32_16x16x32_f16(a1, b0, acc[1][0], 0, 0, 0);
      acc[1][1] = __builtin_amdgcn_mfma_f32_16x16x32_f16(a1, b1, acc[1][1], 0, 0, 0);
    }
  }

  // ---- epilogue: C frag mapping col = lane&15, row = 4*(lane>>4)+reg --------
  int rowb_base = m0 + wr * 32 + 4 * lg;
  int col_base  = n0 + wc * 32 + lr;

  // fused fdot: per-lane a-vec values for this lane's two columns
  float a1v[2], a2v[2];
  float p1[2][4], p2[2][4];
  if (fd) {
    const float* avf = (const float*)avec; const ushortT* avu = (const ushortT*)avec;
#pragma unroll
    for (int fn = 0; fn < 2; fn++) {
      int c = n0 + wc * 32 + fn * 16 + lr;
      a1v[fn] = flg ? avf[avOff + c]       : b2f(avu[avOff + c]);
      a2v[fn] = flg ? avf[avOff + 768 + c] : b2f(avu[avOff + 768 + c]);
    }
#pragma unroll
    for (int fm = 0; fm < 2; fm++)
#pragma unroll
      for (int r = 0; r < 4; r++) { p1[fm][r] = 0.f; p2[fm][r] = 0.f; }
  }

#pragma unroll
  for (int fm = 0; fm < 2; fm++) {
#pragma unroll
    for (int fn = 0; fn < 2; fn++) {
      int rowb = rowb_base + fm * 16;
      int col  = col_base + fn * 16;
      f32x4 v = acc[fm][fn];
      float fullv[4];
      if (MODE == 4) {                       // transposed plain store (Wh1T)
        f16x4 pk;
#pragma unroll
        for (int r = 0; r < 4; r++) { fullv[r] = v[r]; pk[r] = (f16)v[r]; }
        *(f16x4*)((f16*)Cb + (long)col * 1024 + rowb) = pk;
      } else if (MODE == 3) {                // transposed accumulate (Wh2T)
        f16* Cc = (f16*)Cb;
        long idx = (long)col * 1024 + rowb;
        f16x4 pk;
        if (accum) {
          f16x4 old = *(const f16x4*)(Cc + idx);
#pragma unroll
          for (int r = 0; r < 4; r++) { fullv[r] = (float)old[r] + v[r]; pk[r] = (f16)fullv[r]; }
        } else {
#pragma unroll
          for (int r = 0; r < 4; r++) { fullv[r] = v[r]; pk[r] = (f16)v[r]; }
        }
        *(f16x4*)(Cc + idx) = pk;
      } else {
#pragma unroll
        for (int r = 0; r < 4; r++) {
          int row = rowb + r;
          float x = v[r];
          x = x > 0.f ? x : expm1f(x);       // elu (MODE 1 and 2)
          long ci = cOff + (long)row * 768 + col;
          if (MODE == 2) {
            long ri = rOff + (long)row * 768 + col;
            x += flg ? ((const float*)Rb)[ri] : b2f(((const ushortT*)Rb)[ri]);
            if (flg) ((float*)Cb)[ci] = x;
            else     ((ushortT*)Cb)[ci] = f2b(x);
          } else {
            ((f16*)Cb)[ci] = (f16)x;
          }
        }
      }
      if (fd) {
        float ac1 = a1v[fn], ac2 = a2v[fn];
#pragma unroll
        for (int r = 0; r < 4; r++) {
          p1[fm][r] += fullv[r] * ac1;
          p2[fm][r] += fullv[r] * ac2;
        }
      }
    }
  }

  if (fd) {
    // reduce over the 16 col-lanes (lr bits 0..3), then atomicAdd per row
#pragma unroll
    for (int fm = 0; fm < 2; fm++)
#pragma unroll
      for (int r = 0; r < 4; r++) {
#pragma unroll
        for (int o = 1; o < 16; o <<= 1) {
          p1[fm][r] += __shfl_xor(p1[fm][r], o);
          p2[fm][r] += __shfl_xor(p2[fm][r], o);
        }
      }
    if (lr == 0) {
#pragma unroll
      for (int fm = 0; fm < 2; fm++)
#pragma unroll
        for (int r = 0; r < 4; r++) {
          int row = rowb_base + fm * 16 + r;
          atomicAdd(fvec + row, p1[fm][r]);
          atomicAdd(fvec + 1024 + row, p2[fm][r]);
        }
    }
  }
}

// ---- masked row softmax over 1024 cols; one block per row i; f16 out ---------
__global__ __launch_bounds__(256) void attn_kernel(
    const float* __restrict__ f1, const float* __restrict__ f2,
    const int* __restrict__ adj, f16* __restrict__ att) {
  __shared__ float sred[8];
  int i = blockIdx.x;
  const int* arow = adj + (size_t)i * 1024;
  float f1i = f1[i];
  f16* orow = att + (size_t)i * 1024;
  int t = threadIdx.x, lane = t & 63, wid = t >> 6;
  int j0 = t * 4;

  i32x4 av = *(const i32x4*)(arow + j0);
  f32x4 fv = *(const f32x4*)(f2 + j0);

  float e[4];
  int msk[4];
  float mx = -1e38f;
#pragma unroll
  for (int c = 0; c < 4; c++) {
    float ev = f1i + fv[c];
    ev = ev > 0.f ? ev : ALPHA * ev;
    e[c] = ev;
    msk[c] = av[c] > 0;
    if (msk[c]) mx = fmaxf(mx, ev);
  }
#pragma unroll
  for (int o = 32; o > 0; o >>= 1) mx = fmaxf(mx, __shfl_down(mx, o));
  if (lane == 0) sred[wid] = mx;
  __syncthreads();
  float bmx = fmaxf(fmaxf(sred[0], sred[1]), fmaxf(sred[2], sred[3]));
  bool none = bmx < -1e37f;   // all-masked row -> reference softmax is uniform

  float p[4];
  float sum = 0.f;
#pragma unroll
  for (int c = 0; c < 4; c++) {
    p[c] = none ? 1.f : (msk[c] ? expf(e[c] - bmx) : 0.f);
    sum += p[c];
  }
#pragma unroll
  for (int o = 32; o > 0; o >>= 1) sum += __shfl_down(sum, o);
  if (lane == 0) sred[4 + wid] = sum;
  __syncthreads();
  float inv = 1.f / (sred[4] + sred[5] + sred[6] + sred[7]);
  f16x4 pk;
#pragma unroll
  for (int c = 0; c < 4; c++) pk[c] = (f16)(p[c] * inv);
  *(f16x4*)(orow + j0) = pk;
}

// ---- classifier: scores[row] = sigmoid(yy[row]@w + b) * mask[row] ------------
__global__ __launch_bounds__(256) void cls_kernel(
    void* __restrict__ outbase, const void* __restrict__ w,
    const void* __restrict__ bc, const void* __restrict__ mask,
    const int* __restrict__ rflag) {
  int t = threadIdx.x, lane = t & 63, wv = t >> 6;
  long row = (long)blockIdx.x * 4 + wv;    // 0..8191
  int f32 = *rflag;
  const float* yf = (const float*)outbase; const ushortT* yu = (const ushortT*)outbase;
  const float* wf = (const float*)w;       const ushortT* wu = (const ushortT*)w;
  float s = 0.f;
  for (int d = lane; d < 768; d += 64) {
    float yv = f32 ? yf[row * 768 + d] : b2f(yu[row * 768 + d]);
    float wvv = f32 ? wf[d] : b2f(wu[d]);
    s += yv * wvv;
  }
#pragma unroll
  for (int o = 32; o > 0; o >>= 1) s += __shfl_down(s, o);
  if (lane == 0) {
    float bb = f32 ? ((const float*)bc)[0] : b2f(((const ushortT*)bc)[0]);
    float mk = f32 ? ((const float*)mask)[row] : b2f(((const ushortT*)mask)[row]);
    float sig = 1.f / (1.f + expf(-(s + bb)));
    long oi = 6291456L + row;
    if (f32) ((float*)outbase)[oi] = sig * mk;
    else ((ushortT*)outbase)[oi] = f2b(sig * mk);
  }
}

extern "C" void kernel_launch(void* const* d_in, const int* in_sizes, int n_in,
                              void* d_out, int out_size, void* d_ws, size_t ws_size,
                              hipStream_t stream) {
  (void)in_sizes; (void)n_in; (void)out_size; (void)ws_size;

  const void* X    = d_in[0];               // [8,1024,768]
  const int*  adj  = (const int*)d_in[1];   // [8,1024,1024]
  const void* maskN= d_in[2];               // [8,1024]
  const void* Wh   = d_in[3];               // [4,768,768]
  const void* aH   = d_in[4];               // [4,1536]
  const void* Wo   = d_in[5];               // [3072,768]
  const void* aO   = d_in[6];               // [1536]
  const void* wcls = d_in[7];               // [768]
  const void* bcls = d_in[8];               // [1]

  char* ws = (char*)d_ws;
  float* f1   = (float*)(ws + 0);           // [1024] (f2 = f1 + 1024)
  float* f2   = (float*)(ws + 4096);
  int*   flag = (int*)(ws + 8192);
  f16* Wh1T = (f16*)(ws + 8448);            // [768,1024] f16
  f16* Wh2T = (f16*)(ws + 1581312);         // [768,1024] f16
  f16* attb = (f16*)(ws + 3154176);         // [1024,1024] f16
  f16* hout = (f16*)(ws + 5251328);         // [1024,768] f16; end 6,824,192

  detect_dtype<<<1, 256, 0, stream>>>((const ushortT*)X, flag);

  dim3 gg(12, 16);     // N tiles x M tiles (64x64)
  for (int b = 0; b < 8; b++) {
    long xOff = (long)b * 786432;
    for (int h = 0; h < 4; h++) {
      // zero f1/f2 for G1's fused fdot
      hipMemsetAsync(ws, 0, 8192, stream);
      // G1: Wh1T = (X[b] @ W_heads[h])^T, fused f1/f2 = Wh1 @ a1/a2
      mgemm<4, 1><<<gg, 256, 0, stream>>>(
          X, Wh, Wh1T, nullptr, 768, 768, 768, 1,
          xOff, (long)h * 589824, 0L, 0L, 0, aH, (long)h * 1536, 1, f1, flag);
      // A1
      attn_kernel<<<1024, 256, 0, stream>>>(f1, f2, adj + (size_t)b * 1048576, attb);
      // G2: hout = elu(att @ Wh1)
      mgemm<1, 0><<<gg, 256, 0, stream>>>(
          attb, Wh1T, hout, nullptr, 1024, 1024, 0, 0,
          0L, 0L, 0L, 0L, 0, nullptr, 0L, 0, nullptr, flag);
      if (h == 3) hipMemsetAsync(ws, 0, 8192, stream);  // zero for G3's fused fdot
      // G3: Wh2T (+)= (hout @ Wo_slice)^T; at h=3 also fuse f1/f2 = Wh2 @ aO
      mgemm<3, 1><<<gg, 256, 0, stream>>>(
          hout, Wo, Wh2T, nullptr, 768, 768, 768, 0,
          0L, (long)h * 589824, 0L, 0L, h > 0 ? 1 : 0, aO, 0L, h == 3 ? 1 : 0, f1, flag);
    }
    // A2 on layer-2 features
    attn_kernel<<<1024, 256, 0, stream>>>(f1, f2, adj + (size_t)b * 1048576, attb);
    // G4: yy[b] = elu(att2 @ Wh2) + X[b]  -> d_out (flag dtype)
    mgemm<2, 0><<<gg, 256, 0, stream>>>(
        attb, Wh2T, d_out, X, 1024, 1024, 0, 0,
        0L, 0L, xOff, xOff, 0, nullptr, 0L, 0, nullptr, flag);
  }

  cls_kernel<<<2048, 256, 0, stream>>>(d_out, wcls, bcls, maskN, flag);
}

// Round 4
// 1779.420 us; speedup vs baseline: 2.0399x; 1.1047x over previous
//
#include <hip/hip_runtime.h>

// GAT encoder, B=8, N=1024, D=768, H=4. adj int32; float tensors bf16 OR f32,
// runtime-detected (flag in ws). Outputs: yy [B,N,D] then node_scores [B,N].
//
// PIPELINE ROUND (base = round-3 fusion kernel at 1966 us):
//  * mgemm mainloop: double-buffered LDS (2x16KB) + depth-2 register prefetch,
//    ONE barrier per k-tile. Loads for tile kt+2 issued before compute(kt), so
//    the vmcnt drain before the LDS write waits on loads that aged a full
//    compute phase. Removes the exposed ~200-400cyc L2 latency per k-tile.
//  * all 32 hipMemsetAsync(f1/f2) dispatches removed: zeroing is a side-job of
//    block(0,0) in G2/G4 (dead window between attn's read and the next fused
//    fdot's atomics) and of detect_dtype for the first G1.
//  * expf/expm1f -> __expf forms in attn / cls / elu epilogues.
// Dispatches: 186 -> 154.
//
// ws (peak 6,824,192 B, unchanged):
//   f1 f32[1024] @0, f2 @4096, flag @8192,
//   Wh1T f16[768,1024] @8448, Wh2T @1581312, att f16[1024,1024] @3154176,
//   hout f16[1024,768] @5251328 (end 6,824,192).

typedef unsigned short ushortT;
typedef _Float16 f16;
typedef __attribute__((ext_vector_type(8))) _Float16 f16x8;
typedef __attribute__((ext_vector_type(4))) _Float16 f16x4;
typedef __attribute__((ext_vector_type(4))) float f32x4;
typedef __attribute__((ext_vector_type(2))) float f32x2;
typedef __attribute__((ext_vector_type(8))) unsigned short u16x8;
typedef __attribute__((ext_vector_type(2))) unsigned short u16x2;
typedef __attribute__((ext_vector_type(4))) int i32x4;

#define ALPHA 0.2f

__device__ __forceinline__ float b2f(ushortT u) {
  union { unsigned int i; float f; } c; c.i = ((unsigned int)u) << 16; return c.f;
}
__device__ __forceinline__ ushortT f2b(float f) {
  union { float f; unsigned int u; } c; c.f = f;
  unsigned int u = c.u;
  u += 0x7FFFu + ((u >> 16) & 1u);   // RNE
  return (ushortT)(u >> 16);
}

// ---- dtype detector; also zeroes f1/f2 for the first fused-fdot G1 ----------
__global__ void detect_dtype(const ushortT* __restrict__ X, int* __restrict__ flag,
                             float* __restrict__ fvec) {
  __shared__ int s[256];
  int t = threadIdx.x, c = 0;
  for (int i = t; i < 2048; i += 256) fvec[i] = 0.f;   // f1+f2 zero
  for (int i = t; i < 16384; i += 256) {
    int e = (X[2 * i] >> 7) & 0xFF;
    if (e > 140 || e < 100) c++;     // genuine bf16 N(0,1): essentially never
  }
  s[t] = c; __syncthreads();
  for (int o = 128; o > 0; o >>= 1) { if (t < o) s[t] += s[t + o]; __syncthreads(); }
  if (t == 0) *flag = (s[0] > 1000) ? 1 : 0;   // 1 -> inputs are f32
}

// ---- MFMA GEMM: C[1024,768] = A[1024,K] @ B[K,768] --------------------------
// BSRC 0: Bb is BT f16 [768][K] (row stride K), staged with 16B loads.
// BSRC 1: Bb is raw row-major [K][768] (f32/bf16 per flag), transposed into the
//         same swizzled Bs[n][k] layout during staging (coalesced k-row loads).
// aRaw: 1 -> A raw (f32/bf16 per flag), 0 -> f16.
// MODE 1: elu -> f16 (hout). MODE 2: elu + residual(raw) -> flag dtype (yy).
// MODE 3: f16 accumulate, TRANSPOSED store (Wh2T). MODE 4: f16 plain
// TRANSPOSED store (Wh1T).
// fd != 0: fused fdot epilogue (atomicAdd into pre-zeroed fvec/fvec+1024).
// zf != 0: block(0,0) zeroes fvec[0..2047] for the NEXT kernel's fused fdot.
// Mainloop: double-buffered LDS, depth-2 prefetch, one barrier per k-tile.
// Block 256 = 4 waves (2x2 of 32x32), tile BM=64 BN=64 BK=64, grid (12,16).
template <int MODE, int BSRC>
__global__ __launch_bounds__(256) void mgemm(
    const void* __restrict__ Ab, const void* __restrict__ Bb,
    void* __restrict__ Cb, const void* __restrict__ Rb,
    int K, int lda, int ldb, int aRaw,
    long aOff, long bOff, long cOff, long rOff, int accum,
    const void* __restrict__ avec, long avOff, int fd, float* __restrict__ fvec,
    int zf, const int* __restrict__ rflag) {
  __shared__ __align__(16) f16 As[2][64 * 64];
  __shared__ __align__(16) f16 Bs[2][64 * 64];
  int t = threadIdx.x;
  int n0 = blockIdx.x * 64, m0 = blockIdx.y * 64;
  int flg = *rflag;
  int aTy = aRaw ? (flg ? 2 : 1) : 0;   // 0 f16, 1 bf16, 2 f32

  if (zf && blockIdx.x == 0 && blockIdx.y == 0) {
#pragma unroll
    for (int i = 0; i < 8; i++) fvec[t + i * 256] = 0.f;   // f1+f2 for next fd
  }

  // A staging: thread t owns tile row tq, 16-elem k-group cq (2 chunks of 8)
  int tq = t >> 2, cq = t & 3;
  long aBase = aOff + (long)(m0 + tq) * lda + cq * 16;
  int stA0 = tq * 64 + (((2 * cq)     ^ (tq & 7)) * 8);
  int stA1 = tq * 64 + (((2 * cq + 1) ^ (tq & 7)) * 8);

  const f16*     Ah = (const f16*)Ab;
  const ushortT* Au = (const ushortT*)Ab;
  const float*   Af = (const float*)Ab;
  const f16*     Bh = (const f16*)Bb;
  const ushortT* Bu = (const ushortT*)Bb;
  const float*   Bf = (const float*)Bb;

  // B staging geometry
  long bBase = 0;
  int stB0, stB1;
  int q2 = 0, cB = 0;
  if (BSRC == 0) {
    bBase = bOff + (long)(n0 + tq) * (long)K + cq * 16;
    stB0 = stA0; stB1 = stA1;
  } else {
    q2 = t & 31; cB = t >> 5;                 // n-pair 2*q2, chunk cB (0..7)
    int nb0 = 2 * q2, nb1 = nb0 + 1;
    stB0 = nb0 * 64 + ((cB ^ (nb0 & 7)) * 8);
    stB1 = nb1 * 64 + ((cB ^ (nb1 & 7)) * 8);
  }

  f16x8 ra0, ra1, rb0, rb1;   // prefetch regs (SSA-renamed across stages)

  auto loadA = [&](int kt) {
    long g = aBase + (long)kt * 64;
    if (aTy == 0) {
      ra0 = *(const f16x8*)(Ah + g);
      ra1 = *(const f16x8*)(Ah + g + 8);
    } else if (aTy == 1) {
      u16x8 v0 = *(const u16x8*)(Au + g);
      u16x8 v1 = *(const u16x8*)(Au + g + 8);
#pragma unroll
      for (int j = 0; j < 8; j++) { ra0[j] = (f16)b2f(v0[j]); ra1[j] = (f16)b2f(v1[j]); }
    } else {
      f32x4 v0 = *(const f32x4*)(Af + g);
      f32x4 v1 = *(const f32x4*)(Af + g + 4);
      f32x4 v2 = *(const f32x4*)(Af + g + 8);
      f32x4 v3 = *(const f32x4*)(Af + g + 12);
#pragma unroll
      for (int j = 0; j < 4; j++) {
        ra0[j] = (f16)v0[j]; ra0[4 + j] = (f16)v1[j];
        ra1[j] = (f16)v2[j]; ra1[4 + j] = (f16)v3[j];
      }
    }
  };
  auto loadB = [&](int kt) {
    if (BSRC == 0) {
      long g = bBase + (long)kt * 64;
      rb0 = *(const f16x8*)(Bh + g);
      rb1 = *(const f16x8*)(Bh + g + 8);
    } else {
      // raw row-major: rows k = kt*64 + cB*8 + j, cols n0 + 2*q2 (+1)
      long rbase = bOff + (long)(kt * 64 + cB * 8) * ldb + n0 + 2 * q2;
      if (flg) {
#pragma unroll
        for (int j = 0; j < 8; j++) {
          f32x2 v = *(const f32x2*)(Bf + rbase + (long)j * ldb);
          rb0[j] = (f16)v[0]; rb1[j] = (f16)v[1];
        }
      } else {
#pragma unroll
        for (int j = 0; j < 8; j++) {
          u16x2 v = *(const u16x2*)(Bu + rbase + (long)j * ldb);
          rb0[j] = (f16)b2f(v[0]); rb1[j] = (f16)b2f(v[1]);
        }
      }
    }
  };
  auto stage = [&](int buf) {
    *(f16x8*)(&As[buf][0] + stA0) = ra0;  *(f16x8*)(&As[buf][0] + stA1) = ra1;
    *(f16x8*)(&Bs[buf][0] + stB0) = rb0;  *(f16x8*)(&Bs[buf][0] + stB1) = rb1;
  };

  // compute-side lane geometry
  int lane = t & 63, wid = t >> 6;
  int wr = wid >> 1, wc = wid & 1;            // 2x2 waves of 32x32
  int lr = lane & 15, lg = lane >> 4, l7 = lane & 7;
  int aRow0 = (wr * 32 + lr) * 64, aRow1 = aRow0 + 16 * 64;
  int bRow0 = (wc * 32 + lr) * 64, bRow1 = bRow0 + 16 * 64;
  int ch0 = ((lg) ^ l7) * 8, ch1 = ((4 + lg) ^ l7) * 8;   // swizzled chunks kk=0,1

  f32x4 acc[2][2];
#pragma unroll
  for (int i = 0; i < 2; i++)
#pragma unroll
    for (int j = 0; j < 2; j++) acc[i][j] = (f32x4){0.f, 0.f, 0.f, 0.f};

  int KT = K >> 6;
  // prologue: tile0 -> buf0; issue tile1 loads; barrier
  loadA(0); loadB(0);
  stage(0);
  loadA(1); loadB(1);
  __syncthreads();

  for (int kt = 0; kt < KT; ++kt) {
    int cur = kt & 1;
    if (kt + 1 < KT) stage(cur ^ 1);                  // stage tile kt+1 (other buf)
    if (kt + 2 < KT) { loadA(kt + 2); loadB(kt + 2); } // issue 2 tiles ahead
#pragma unroll
    for (int kk = 0; kk < 2; kk++) {
      int ch = kk ? ch1 : ch0;
      f16x8 a0 = *(const f16x8*)(&As[cur][0] + aRow0 + ch);
      f16x8 a1 = *(const f16x8*)(&As[cur][0] + aRow1 + ch);
      f16x8 b0 = *(const f16x8*)(&Bs[cur][0] + bRow0 + ch);
      f16x8 b1 = *(const f16x8*)(&Bs[cur][0] + bRow1 + ch);
      acc[0][0] = __builtin_amdgcn_mfma_f32_16x16x32_f16(a0, b0, acc[0][0], 0, 0, 0);
      acc[0][1] = __builtin_amdgcn_mfma_f32_16x16x32_f16(a0, b1, acc[0][1], 0, 0, 0);
      acc[1][0] = __builtin_amdgcn_mfma_f32_16x16x32_f16(a1, b0, acc[1][0], 0, 0, 0);
      acc[1][1] = __builtin_amdgcn_mfma_f32_16x16x32_f16(a1, b1, acc[1][1], 0, 0, 0);
    }
    __syncthreads();   // readers of buf[cur] done; writes to buf[cur^1] visible
  }

  // ---- epilogue: C frag mapping col = lane&15, row = 4*(lane>>4)+reg --------
  int rowb_base = m0 + wr * 32 + 4 * lg;
  int col_base  = n0 + wc * 32 + lr;

  // fused fdot: per-lane a-vec values for this lane's two columns
  float a1v[2], a2v[2];
  float p1[2][4], p2[2][4];
  if (fd) {
    const float* avf = (const float*)avec; const ushortT* avu = (const ushortT*)avec;
#pragma unroll
    for (int fn = 0; fn < 2; fn++) {
      int c = n0 + wc * 32 + fn * 16 + lr;
      a1v[fn] = flg ? avf[avOff + c]       : b2f(avu[avOff + c]);
      a2v[fn] = flg ? avf[avOff + 768 + c] : b2f(avu[avOff + 768 + c]);
    }
#pragma unroll
    for (int fm = 0; fm < 2; fm++)
#pragma unroll
      for (int r = 0; r < 4; r++) { p1[fm][r] = 0.f; p2[fm][r] = 0.f; }
  }

#pragma unroll
  for (int fm = 0; fm < 2; fm++) {
#pragma unroll
    for (int fn = 0; fn < 2; fn++) {
      int rowb = rowb_base + fm * 16;
      int col  = col_base + fn * 16;
      f32x4 v = acc[fm][fn];
      float fullv[4];
      if (MODE == 4) {                       // transposed plain store (Wh1T)
        f16x4 pk;
#pragma unroll
        for (int r = 0; r < 4; r++) { fullv[r] = v[r]; pk[r] = (f16)v[r]; }
        *(f16x4*)((f16*)Cb + (long)col * 1024 + rowb) = pk;
      } else if (MODE == 3) {                // transposed accumulate (Wh2T)
        f16* Cc = (f16*)Cb;
        long idx = (long)col * 1024 + rowb;
        f16x4 pk;
        if (accum) {
          f16x4 old = *(const f16x4*)(Cc + idx);
#pragma unroll
          for (int r = 0; r < 4; r++) { fullv[r] = (float)old[r] + v[r]; pk[r] = (f16)fullv[r]; }
        } else {
#pragma unroll
          for (int r = 0; r < 4; r++) { fullv[r] = v[r]; pk[r] = (f16)v[r]; }
        }
        *(f16x4*)(Cc + idx) = pk;
      } else {
#pragma unroll
        for (int r = 0; r < 4; r++) {
          int row = rowb + r;
          float x = v[r];
          x = x > 0.f ? x : __expf(x) - 1.f;   // elu (MODE 1 and 2)
          long ci = cOff + (long)row * 768 + col;
          if (MODE == 2) {
            long ri = rOff + (long)row * 768 + col;
            x += flg ? ((const float*)Rb)[ri] : b2f(((const ushortT*)Rb)[ri]);
            if (flg) ((float*)Cb)[ci] = x;
            else     ((ushortT*)Cb)[ci] = f2b(x);
          } else {
            ((f16*)Cb)[ci] = (f16)x;
          }
        }
      }
      if (fd) {
        float ac1 = a1v[fn], ac2 = a2v[fn];
#pragma unroll
        for (int r = 0; r < 4; r++) {
          p1[fm][r] += fullv[r] * ac1;
          p2[fm][r] += fullv[r] * ac2;
        }
      }
    }
  }

  if (fd) {
    // reduce over the 16 col-lanes (lr bits 0..3), then atomicAdd per row
#pragma unroll
    for (int fm = 0; fm < 2; fm++)
#pragma unroll
      for (int r = 0; r < 4; r++) {
#pragma unroll
        for (int o = 1; o < 16; o <<= 1) {
          p1[fm][r] += __shfl_xor(p1[fm][r], o);
          p2[fm][r] += __shfl_xor(p2[fm][r], o);
        }
      }
    if (lr == 0) {
#pragma unroll
      for (int fm = 0; fm < 2; fm++)
#pragma unroll
        for (int r = 0; r < 4; r++) {
          int row = rowb_base + fm * 16 + r;
          atomicAdd(fvec + row, p1[fm][r]);
          atomicAdd(fvec + 1024 + row, p2[fm][r]);
        }
    }
  }
}

// ---- masked row softmax over 1024 cols; one block per row i; f16 out ---------
__global__ __launch_bounds__(256) void attn_kernel(
    const float* __restrict__ f1, const float* __restrict__ f2,
    const int* __restrict__ adj, f16* __restrict__ att) {
  __shared__ float sred[8];
  int i = blockIdx.x;
  const int* arow = adj + (size_t)i * 1024;
  float f1i = f1[i];
  f16* orow = att + (size_t)i * 1024;
  int t = threadIdx.x, lane = t & 63, wid = t >> 6;
  int j0 = t * 4;

  i32x4 av = *(const i32x4*)(arow + j0);
  f32x4 fv = *(const f32x4*)(f2 + j0);

  float e[4];
  int msk[4];
  float mx = -1e38f;
#pragma unroll
  for (int c = 0; c < 4; c++) {
    float ev = f1i + fv[c];
    ev = ev > 0.f ? ev : ALPHA * ev;
    e[c] = ev;
    msk[c] = av[c] > 0;
    if (msk[c]) mx = fmaxf(mx, ev);
  }
#pragma unroll
  for (int o = 32; o > 0; o >>= 1) mx = fmaxf(mx, __shfl_down(mx, o));
  if (lane == 0) sred[wid] = mx;
  __syncthreads();
  float bmx = fmaxf(fmaxf(sred[0], sred[1]), fmaxf(sred[2], sred[3]));
  bool none = bmx < -1e37f;   // all-masked row -> reference softmax is uniform

  float p[4];
  float sum = 0.f;
#pragma unroll
  for (int c = 0; c < 4; c++) {
    p[c] = none ? 1.f : (msk[c] ? __expf(e[c] - bmx) : 0.f);
    sum += p[c];
  }
#pragma unroll
  for (int o = 32; o > 0; o >>= 1) sum += __shfl_down(sum, o);
  if (lane == 0) sred[4 + wid] = sum;
  __syncthreads();
  float inv = 1.f / (sred[4] + sred[5] + sred[6] + sred[7]);
  f16x4 pk;
#pragma unroll
  for (int c = 0; c < 4; c++) pk[c] = (f16)(p[c] * inv);
  *(f16x4*)(orow + j0) = pk;
}

// ---- classifier: scores[row] = sigmoid(yy[row]@w + b) * mask[row] ------------
__global__ __launch_bounds__(256) void cls_kernel(
    void* __restrict__ outbase, const void* __restrict__ w,
    const void* __restrict__ bc, const void* __restrict__ mask,
    const int* __restrict__ rflag) {
  int t = threadIdx.x, lane = t & 63, wv = t >> 6;
  long row = (long)blockIdx.x * 4 + wv;    // 0..8191
  int f32 = *rflag;
  const float* yf = (const float*)outbase; const ushortT* yu = (const ushortT*)outbase;
  const float* wf = (const float*)w;       const ushortT* wu = (const ushortT*)w;
  float s = 0.f;
  for (int d = lane; d < 768; d += 64) {
    float yv = f32 ? yf[row * 768 + d] : b2f(yu[row * 768 + d]);
    float wvv = f32 ? wf[d] : b2f(wu[d]);
    s += yv * wvv;
  }
#pragma unroll
  for (int o = 32; o > 0; o >>= 1) s += __shfl_down(s, o);
  if (lane == 0) {
    float bb = f32 ? ((const float*)bc)[0] : b2f(((const ushortT*)bc)[0]);
    float mk = f32 ? ((const float*)mask)[row] : b2f(((const ushortT*)mask)[row]);
    float sig = 1.f / (1.f + __expf(-(s + bb)));
    long oi = 6291456L + row;
    if (f32) ((float*)outbase)[oi] = sig * mk;
    else ((ushortT*)outbase)[oi] = f2b(sig * mk);
  }
}

extern "C" void kernel_launch(void* const* d_in, const int* in_sizes, int n_in,
                              void* d_out, int out_size, void* d_ws, size_t ws_size,
                              hipStream_t stream) {
  (void)in_sizes; (void)n_in; (void)out_size; (void)ws_size;

  const void* X    = d_in[0];               // [8,1024,768]
  const int*  adj  = (const int*)d_in[1];   // [8,1024,1024]
  const void* maskN= d_in[2];               // [8,1024]
  const void* Wh   = d_in[3];               // [4,768,768]
  const void* aH   = d_in[4];               // [4,1536]
  const void* Wo   = d_in[5];               // [3072,768]
  const void* aO   = d_in[6];               // [1536]
  const void* wcls = d_in[7];               // [768]
  const void* bcls = d_in[8];               // [1]

  char* ws = (char*)d_ws;
  float* f1   = (float*)(ws + 0);           // [1024] (f2 = f1 + 1024)
  float* f2   = (float*)(ws + 4096);
  int*   flag = (int*)(ws + 8192);
  f16* Wh1T = (f16*)(ws + 8448);            // [768,1024] f16
  f16* Wh2T = (f16*)(ws + 1581312);         // [768,1024] f16
  f16* attb = (f16*)(ws + 3154176);         // [1024,1024] f16
  f16* hout = (f16*)(ws + 5251328);         // [1024,768] f16; end 6,824,192

  detect_dtype<<<1, 256, 0, stream>>>((const ushortT*)X, flag, f1);

  dim3 gg(12, 16);     // N tiles x M tiles (64x64)
  for (int b = 0; b < 8; b++) {
    long xOff = (long)b * 786432;
    for (int h = 0; h < 4; h++) {
      // G1: Wh1T = (X[b] @ W_heads[h])^T, fused f1/f2 = Wh1 @ a1/a2
      mgemm<4, 1><<<gg, 256, 0, stream>>>(
          X, Wh, Wh1T, nullptr, 768, 768, 768, 1,
          xOff, (long)h * 589824, 0L, 0L, 0, aH, (long)h * 1536, 1, f1, 0, flag);
      // A1
      attn_kernel<<<1024, 256, 0, stream>>>(f1, f2, adj + (size_t)b * 1048576, attb);
      // G2: hout = elu(att @ Wh1); block(0,0) re-zeroes f1/f2 for next fd user
      mgemm<1, 0><<<gg, 256, 0, stream>>>(
          attb, Wh1T, hout, nullptr, 1024, 1024, 0, 0,
          0L, 0L, 0L, 0L, 0, nullptr, 0L, 0, f1, 1, flag);
      // G3: Wh2T (+)= (hout @ Wo_slice)^T; at h=3 also fuse f1/f2 = Wh2 @ aO
      mgemm<3, 1><<<gg, 256, 0, stream>>>(
          hout, Wo, Wh2T, nullptr, 768, 768, 768, 0,
          0L, (long)h * 589824, 0L, 0L, h > 0 ? 1 : 0, aO, 0L, h == 3 ? 1 : 0, f1, 0, flag);
    }
    // A2 on layer-2 features
    attn_kernel<<<1024, 256, 0, stream>>>(f1, f2, adj + (size_t)b * 1048576, attb);
    // G4: yy[b] = elu(att2 @ Wh2) + X[b] -> d_out; block(0,0) zeroes f1/f2
    mgemm<2, 0><<<gg, 256, 0, stream>>>(
        attb, Wh2T, d_out, X, 1024, 1024, 0, 0,
        0L, 0L, xOff, xOff, 0, nullptr, 0L, 0, f1, 1, flag);
  }

  cls_kernel<<<2048, 256, 0, stream>>>(d_out, wcls, bcls, maskN, flag);
}

// Round 5
// 1480.141 us; speedup vs baseline: 2.4524x; 1.2022x over previous
//
#include <hip/hip_runtime.h>

// GAT encoder, B=8, N=1024, D=768, H=4. adj int32; float tensors bf16 OR f32,
// runtime-detected (flag in ws). Outputs: yy [B,N,D] then node_scores [B,N].
//
// PAIRING + GLOAD ROUND (base = round-4 at 1779 us):
//  * Independent GEMMs merged into grid.z=2 dispatches: (G3[h] || G1[h+1]) and
//    (G4[b] || G1[0,b+1]) -> 384-block launches (1.5 blocks/CU, TLP hides the
//    per-tile barrier/load stalls that dominate at 1 block/CU). 146->115
//    dispatches.
//  * f1/f2 ping-pong: buffer P in ws (@0), buffer Q in d_out's scores region
//    (8KB; scores only written by cls at the very end; dtype offset resolved
//    from flag inside kernels). G2[h]'s spare block zeroes the next fdot
//    target (h<3: one buffer; h==3: both). Verified for both b-parities.
//  * G2/G4 (all-f16, K=1024) staging via __builtin_amdgcn_global_load_lds
//    width-16: XOR-swizzle folded into the per-lane GLOBAL source address,
//    LDS dest linear (guide rule 21). No VGPR round-trip, no ds_writes.
//  * G1/G3 (raw/strided B) keep the proven register double-buffer staging.
//
// ws (peak 6,824,192 B, unchanged):
//   f1 f32[1024] @0, f2 @4096, flag @8192,
//   Wh1T f16[768,1024] @8448, Wh2T @1581312, att f16[1024,1024] @3154176,
//   hout f16[1024,768] @5251328 (end 6,824,192).

typedef unsigned short ushortT;
typedef _Float16 f16;
typedef __attribute__((ext_vector_type(8))) _Float16 f16x8;
typedef __attribute__((ext_vector_type(4))) _Float16 f16x4;
typedef __attribute__((ext_vector_type(4))) float f32x4;
typedef __attribute__((ext_vector_type(2))) float f32x2;
typedef __attribute__((ext_vector_type(8))) unsigned short u16x8;
typedef __attribute__((ext_vector_type(2))) unsigned short u16x2;
typedef __attribute__((ext_vector_type(4))) int i32x4;

#define ALPHA 0.2f

__device__ __forceinline__ float b2f(ushortT u) {
  union { unsigned int i; float f; } c; c.i = ((unsigned int)u) << 16; return c.f;
}
__device__ __forceinline__ ushortT f2b(float f) {
  union { float f; unsigned int u; } c; c.f = f;
  unsigned int u = c.u;
  u += 0x7FFFu + ((u >> 16) & 1u);   // RNE
  return (ushortT)(u >> 16);
}
// Q buffer (f1/f2 set #2) lives at the start of d_out's scores region.
__device__ __forceinline__ float* qbuf(char* dout, int flg) {
  return (float*)(dout + (flg ? 25165824L : 12582912L));
}
__device__ __forceinline__ void gld16(const f16* g, f16* l) {
  __builtin_amdgcn_global_load_lds(
      (const __attribute__((address_space(1))) void*)g,
      (__attribute__((address_space(3))) void*)l, 16, 0, 0);
}

// ---- dtype detector; zeroes P and Q for the first fused-fdot users ----------
__global__ void detect_dtype(const ushortT* __restrict__ X, int* __restrict__ flag,
                             float* __restrict__ Pws, char* __restrict__ dout) {
  __shared__ int s[256];
  int t = threadIdx.x, c = 0;
  for (int i = t; i < 16384; i += 256) {
    int e = (X[2 * i] >> 7) & 0xFF;
    if (e > 140 || e < 100) c++;     // genuine bf16 N(0,1): essentially never
  }
  s[t] = c; __syncthreads();
  for (int o = 128; o > 0; o >>= 1) { if (t < o) s[t] += s[t + o]; __syncthreads(); }
  __syncthreads();
  int fl = (s[0] > 1000) ? 1 : 0;    // 1 -> inputs are f32
  if (t == 0) *flag = fl;
  float* Qv = qbuf(dout, fl);
#pragma unroll
  for (int i = 0; i < 8; i++) { Pws[t + i * 256] = 0.f; Qv[t + i * 256] = 0.f; }
}

// ---- GEMM body: C[1024,768] = A[1024,K] @ B[K,768] --------------------------
struct GA {
  const void* A; const void* B; void* C; const void* R; const void* avec;
  long aOff, bOff, cOff, rOff, avOff;
  int K, lda, ldb, aRaw, accum, fd, fsel, zmask;
};

// BSRC 0: B is BT f16 [768][K] (row stride K); A f16. BOTH staged via
//         global_load_lds w=16 with source-side swizzle.
// BSRC 1: B raw row-major [K][768] (f32/bf16), transposed during register
//         staging; A per aRaw. Register double-buffer, depth-2 prefetch.
// MODE 1: elu -> f16 (hout). MODE 2: elu + residual(raw) -> flag dtype (yy).
// MODE 3: f16 accumulate, transposed store (Wh2T). MODE 4: f16 transposed
// store (Wh1T). fd: fused fdot -> fv (P or Q per fsel). zmask: spare block
// zeroes P (bit0) / Q (bit1).
template <int MODE, int BSRC>
__device__ void gbody(const GA a, float* Pws, char* dout, int flg,
                      f16* AS, f16* BS) {
  int t = threadIdx.x;
  int n0 = blockIdx.x * 64, m0 = blockIdx.y * 64;
  int aTy = a.aRaw ? (flg ? 2 : 1) : 0;   // 0 f16, 1 bf16, 2 f32
  float* fv = a.fsel ? qbuf(dout, flg) : Pws;

  if (a.zmask && blockIdx.x == 0 && blockIdx.y == 0) {
    if (a.zmask & 1) {
#pragma unroll
      for (int i = 0; i < 8; i++) Pws[t + i * 256] = 0.f;
    }
    if (a.zmask & 2) {
      float* Qv = qbuf(dout, flg);
#pragma unroll
      for (int i = 0; i < 8; i++) Qv[t + i * 256] = 0.f;
    }
  }

  const f16*     Ah = (const f16*)a.A;
  const ushortT* Au = (const ushortT*)a.A;
  const float*   Af = (const float*)a.A;
  const f16*     Bh = (const f16*)a.B;
  const ushortT* Bu = (const ushortT*)a.B;
  const float*   Bf = (const float*)a.B;

  // compute-side lane geometry (shared by both staging paths)
  int lane = t & 63, wid = t >> 6;
  int wr = wid >> 1, wc = wid & 1;            // 2x2 waves of 32x32
  int lr = lane & 15, lg = lane >> 4, l7 = lane & 7;
  int aRow0 = (wr * 32 + lr) * 64, aRow1 = aRow0 + 16 * 64;
  int bRow0 = (wc * 32 + lr) * 64, bRow1 = bRow0 + 16 * 64;
  int ch0 = ((lg) ^ l7) * 8, ch1 = ((4 + lg) ^ l7) * 8;

  f32x4 acc[2][2];
#pragma unroll
  for (int i = 0; i < 2; i++)
#pragma unroll
    for (int j = 0; j < 2; j++) acc[i][j] = (f32x4){0.f, 0.f, 0.f, 0.f};

  auto compute = [&](int cur) {
    f16* Ac = AS + cur * 4096; f16* Bc = BS + cur * 4096;
#pragma unroll
    for (int kk = 0; kk < 2; kk++) {
      int ch = kk ? ch1 : ch0;
      f16x8 a0 = *(const f16x8*)(Ac + aRow0 + ch);
      f16x8 a1 = *(const f16x8*)(Ac + aRow1 + ch);
      f16x8 b0 = *(const f16x8*)(Bc + bRow0 + ch);
      f16x8 b1 = *(const f16x8*)(Bc + bRow1 + ch);
      acc[0][0] = __builtin_amdgcn_mfma_f32_16x16x32_f16(a0, b0, acc[0][0], 0, 0, 0);
      acc[0][1] = __builtin_amdgcn_mfma_f32_16x16x32_f16(a0, b1, acc[0][1], 0, 0, 0);
      acc[1][0] = __builtin_amdgcn_mfma_f32_16x16x32_f16(a1, b0, acc[1][0], 0, 0, 0);
      acc[1][1] = __builtin_amdgcn_mfma_f32_16x16x32_f16(a1, b1, acc[1][1], 0, 0, 0);
    }
  };

  int KT = a.K >> 6;

  if (BSRC == 0) {
    // ---- global_load_lds staging: waves 0/1 -> A, waves 2/3 -> B ------------
    // lane l covers LDS row gr=l>>3, chunk gc=l&7; source pre-swizzled so
    // LDS[row][gc] holds logical chunk gc^(row&7)  (rule 21: linear dest).
    int gr = lane >> 3, gcn = lane & 7, swz = (gcn ^ (gr & 7)) * 8;
    int isB = wid >> 1, cq4 = (wid & 1) * 4;
    long gA = a.aOff + (long)(m0 + gr) * a.lda + swz;
    long gB = a.bOff + (long)(n0 + gr) * (long)a.K + swz;
    auto stageG = [&](int buf, int kt) {
      if (!isB) {
        const f16* g = Ah + gA + (long)kt * 64;
        f16* dst = AS + buf * 4096;
#pragma unroll
        for (int c = 0; c < 4; c++)
          gld16(g + (long)(cq4 + c) * 8 * a.lda, dst + (cq4 + c) * 512);
      } else {
        const f16* g = Bh + gB + (long)kt * 64;
        f16* dst = BS + buf * 4096;
#pragma unroll
        for (int c = 0; c < 4; c++)
          gld16(g + (long)(cq4 + c) * 8 * a.K, dst + (cq4 + c) * 512);
      }
    };
    stageG(0, 0);
    __syncthreads();                       // vmcnt(0) drain -> buf0 ready
    for (int kt = 0; kt < KT; ++kt) {
      int cur = kt & 1;
      if (kt + 1 < KT) stageG(cur ^ 1, kt + 1);   // issue; lands during compute
      compute(cur);
      __syncthreads();
    }
  } else {
    // ---- register staging (round-4 proven path) -----------------------------
    int tq = t >> 2, cq = t & 3;
    long aBase = a.aOff + (long)(m0 + tq) * a.lda + cq * 16;
    int stA0 = tq * 64 + (((2 * cq)     ^ (tq & 7)) * 8);
    int stA1 = tq * 64 + (((2 * cq + 1) ^ (tq & 7)) * 8);
    int q2 = t & 31, cB = t >> 5;
    int nb0 = 2 * q2, nb1 = nb0 + 1;
    int stB0 = nb0 * 64 + ((cB ^ (nb0 & 7)) * 8);
    int stB1 = nb1 * 64 + ((cB ^ (nb1 & 7)) * 8);

    f16x8 ra0, ra1, rb0, rb1;
    auto loadA = [&](int kt) {
      long g = aBase + (long)kt * 64;
      if (aTy == 0) {
        ra0 = *(const f16x8*)(Ah + g);
        ra1 = *(const f16x8*)(Ah + g + 8);
      } else if (aTy == 1) {
        u16x8 v0 = *(const u16x8*)(Au + g);
        u16x8 v1 = *(const u16x8*)(Au + g + 8);
#pragma unroll
        for (int j = 0; j < 8; j++) { ra0[j] = (f16)b2f(v0[j]); ra1[j] = (f16)b2f(v1[j]); }
      } else {
        f32x4 v0 = *(const f32x4*)(Af + g);
        f32x4 v1 = *(const f32x4*)(Af + g + 4);
        f32x4 v2 = *(const f32x4*)(Af + g + 8);
        f32x4 v3 = *(const f32x4*)(Af + g + 12);
#pragma unroll
        for (int j = 0; j < 4; j++) {
          ra0[j] = (f16)v0[j]; ra0[4 + j] = (f16)v1[j];
          ra1[j] = (f16)v2[j]; ra1[4 + j] = (f16)v3[j];
        }
      }
    };
    auto loadB = [&](int kt) {
      long rbase = a.bOff + (long)(kt * 64 + cB * 8) * a.ldb + n0 + 2 * q2;
      if (flg) {
#pragma unroll
        for (int j = 0; j < 8; j++) {
          f32x2 v = *(const f32x2*)(Bf + rbase + (long)j * a.ldb);
          rb0[j] = (f16)v[0]; rb1[j] = (f16)v[1];
        }
      } else {
#pragma unroll
        for (int j = 0; j < 8; j++) {
          u16x2 v = *(const u16x2*)(Bu + rbase + (long)j * a.ldb);
          rb0[j] = (f16)b2f(v[0]); rb1[j] = (f16)b2f(v[1]);
        }
      }
    };
    auto stage = [&](int buf) {
      *(f16x8*)(AS + buf * 4096 + stA0) = ra0;
      *(f16x8*)(AS + buf * 4096 + stA1) = ra1;
      *(f16x8*)(BS + buf * 4096 + stB0) = rb0;
      *(f16x8*)(BS + buf * 4096 + stB1) = rb1;
    };
    loadA(0); loadB(0);
    stage(0);
    loadA(1); loadB(1);
    __syncthreads();
    for (int kt = 0; kt < KT; ++kt) {
      int cur = kt & 1;
      if (kt + 1 < KT) stage(cur ^ 1);
      if (kt + 2 < KT) { loadA(kt + 2); loadB(kt + 2); }
      compute(cur);
      __syncthreads();
    }
  }

  // ---- epilogue: C frag mapping col = lane&15, row = 4*(lane>>4)+reg --------
  int rowb_base = m0 + wr * 32 + 4 * lg;
  int col_base  = n0 + wc * 32 + lr;

  float a1v[2], a2v[2];
  float p1[2][4], p2[2][4];
  if (a.fd) {
    const float* avf = (const float*)a.avec; const ushortT* avu = (const ushortT*)a.avec;
#pragma unroll
    for (int fn = 0; fn < 2; fn++) {
      int c = n0 + wc * 32 + fn * 16 + lr;
      a1v[fn] = flg ? avf[a.avOff + c]       : b2f(avu[a.avOff + c]);
      a2v[fn] = flg ? avf[a.avOff + 768 + c] : b2f(avu[a.avOff + 768 + c]);
    }
#pragma unroll
    for (int fm = 0; fm < 2; fm++)
#pragma unroll
      for (int r = 0; r < 4; r++) { p1[fm][r] = 0.f; p2[fm][r] = 0.f; }
  }

#pragma unroll
  for (int fm = 0; fm < 2; fm++) {
#pragma unroll
    for (int fn = 0; fn < 2; fn++) {
      int rowb = rowb_base + fm * 16;
      int col  = col_base + fn * 16;
      f32x4 v = acc[fm][fn];
      float fullv[4];
      if (MODE == 4) {
        f16x4 pk;
#pragma unroll
        for (int r = 0; r < 4; r++) { fullv[r] = v[r]; pk[r] = (f16)v[r]; }
        *(f16x4*)((f16*)a.C + (long)col * 1024 + rowb) = pk;
      } else if (MODE == 3) {
        f16* Cc = (f16*)a.C;
        long idx = (long)col * 1024 + rowb;
        f16x4 pk;
        if (a.accum) {
          f16x4 old = *(const f16x4*)(Cc + idx);
#pragma unroll
          for (int r = 0; r < 4; r++) { fullv[r] = (float)old[r] + v[r]; pk[r] = (f16)fullv[r]; }
        } else {
#pragma unroll
          for (int r = 0; r < 4; r++) { fullv[r] = v[r]; pk[r] = (f16)v[r]; }
        }
        *(f16x4*)(Cc + idx) = pk;
      } else {
#pragma unroll
        for (int r = 0; r < 4; r++) {
          int row = rowb + r;
          float x = v[r];
          x = x > 0.f ? x : __expf(x) - 1.f;   // elu (MODE 1 and 2)
          long ci = a.cOff + (long)row * 768 + col;
          if (MODE == 2) {
            long ri = a.rOff + (long)row * 768 + col;
            x += flg ? ((const float*)a.R)[ri] : b2f(((const ushortT*)a.R)[ri]);
            if (flg) ((float*)a.C)[ci] = x;
            else     ((ushortT*)a.C)[ci] = f2b(x);
          } else {
            ((f16*)a.C)[ci] = (f16)x;
          }
        }
      }
      if (a.fd) {
        float ac1 = a1v[fn], ac2 = a2v[fn];
#pragma unroll
        for (int r = 0; r < 4; r++) {
          p1[fm][r] += fullv[r] * ac1;
          p2[fm][r] += fullv[r] * ac2;
        }
      }
    }
  }

  if (a.fd) {
#pragma unroll
    for (int fm = 0; fm < 2; fm++)
#pragma unroll
      for (int r = 0; r < 4; r++) {
#pragma unroll
        for (int o = 1; o < 16; o <<= 1) {
          p1[fm][r] += __shfl_xor(p1[fm][r], o);
          p2[fm][r] += __shfl_xor(p2[fm][r], o);
        }
      }
    if (lr == 0) {
#pragma unroll
      for (int fm = 0; fm < 2; fm++)
#pragma unroll
        for (int r = 0; r < 4; r++) {
          int row = rowb_base + fm * 16 + r;
          atomicAdd(fv + row, p1[fm][r]);
          atomicAdd(fv + 1024 + row, p2[fm][r]);
        }
    }
  }
}

template <int MODE, int BSRC>
__global__ __launch_bounds__(256) void k_solo(GA a, float* Pws, char* dout,
                                              const int* __restrict__ rflag) {
  __shared__ __align__(16) f16 As[2][4096];
  __shared__ __align__(16) f16 Bs[2][4096];
  gbody<MODE, BSRC>(a, Pws, dout, *rflag, &As[0][0], &Bs[0][0]);
}
// (G3[h] || G1[h+1]) : both register-staged
__global__ __launch_bounds__(256) void k_pair31(GA g3, GA g1, float* Pws, char* dout,
                                                const int* __restrict__ rflag) {
  __shared__ __align__(16) f16 As[2][4096];
  __shared__ __align__(16) f16 Bs[2][4096];
  int flg = *rflag;
  if (blockIdx.z == 0) gbody<3, 1>(g3, Pws, dout, flg, &As[0][0], &Bs[0][0]);
  else                 gbody<4, 1>(g1, Pws, dout, flg, &As[0][0], &Bs[0][0]);
}
// (G4[b] || G1[0,b+1])
__global__ __launch_bounds__(256) void k_pair41(GA g4, GA g1, float* Pws, char* dout,
                                                const int* __restrict__ rflag) {
  __shared__ __align__(16) f16 As[2][4096];
  __shared__ __align__(16) f16 Bs[2][4096];
  int flg = *rflag;
  if (blockIdx.z == 0) gbody<2, 0>(g4, Pws, dout, flg, &As[0][0], &Bs[0][0]);
  else                 gbody<4, 1>(g1, Pws, dout, flg, &As[0][0], &Bs[0][0]);
}

// ---- masked row softmax over 1024 cols; one block per row i; f16 out ---------
__global__ __launch_bounds__(256) void attn_kernel(
    const float* __restrict__ Pws, char* __restrict__ dout, int fsel,
    const int* __restrict__ adj, f16* __restrict__ att,
    const int* __restrict__ rflag) {
  __shared__ float sred[8];
  int flg = *rflag;
  const float* fvb = fsel ? qbuf(dout, flg) : Pws;
  const float* f1 = fvb;
  const float* f2 = fvb + 1024;
  int i = blockIdx.x;
  const int* arow = adj + (size_t)i * 1024;
  float f1i = f1[i];
  f16* orow = att + (size_t)i * 1024;
  int t = threadIdx.x, lane = t & 63, wid = t >> 6;
  int j0 = t * 4;

  i32x4 av = *(const i32x4*)(arow + j0);
  f32x4 fvv = *(const f32x4*)(f2 + j0);

  float e[4];
  int msk[4];
  float mx = -1e38f;
#pragma unroll
  for (int c = 0; c < 4; c++) {
    float ev = f1i + fvv[c];
    ev = ev > 0.f ? ev : ALPHA * ev;
    e[c] = ev;
    msk[c] = av[c] > 0;
    if (msk[c]) mx = fmaxf(mx, ev);
  }
#pragma unroll
  for (int o = 32; o > 0; o >>= 1) mx = fmaxf(mx, __shfl_down(mx, o));
  if (lane == 0) sred[wid] = mx;
  __syncthreads();
  float bmx = fmaxf(fmaxf(sred[0], sred[1]), fmaxf(sred[2], sred[3]));
  bool none = bmx < -1e37f;   // all-masked row -> reference softmax is uniform

  float p[4];
  float sum = 0.f;
#pragma unroll
  for (int c = 0; c < 4; c++) {
    p[c] = none ? 1.f : (msk[c] ? __expf(e[c] - bmx) : 0.f);
    sum += p[c];
  }
#pragma unroll
  for (int o = 32; o > 0; o >>= 1) sum += __shfl_down(sum, o);
  if (lane == 0) sred[4 + wid] = sum;
  __syncthreads();
  float inv = 1.f / (sred[4] + sred[5] + sred[6] + sred[7]);
  f16x4 pk;
#pragma unroll
  for (int c = 0; c < 4; c++) pk[c] = (f16)(p[c] * inv);
  *(f16x4*)(orow + j0) = pk;
}

// ---- classifier: scores[row] = sigmoid(yy[row]@w + b) * mask[row] ------------
__global__ __launch_bounds__(256) void cls_kernel(
    void* __restrict__ outbase, const void* __restrict__ w,
    const void* __restrict__ bc, const void* __restrict__ mask,
    const int* __restrict__ rflag) {
  int t = threadIdx.x, lane = t & 63, wv = t >> 6;
  long row = (long)blockIdx.x * 4 + wv;    // 0..8191
  int f32 = *rflag;
  const float* yf = (const float*)outbase; const ushortT* yu = (const ushortT*)outbase;
  const float* wf = (const float*)w;       const ushortT* wu = (const ushortT*)w;
  float s = 0.f;
  for (int d = lane; d < 768; d += 64) {
    float yv = f32 ? yf[row * 768 + d] : b2f(yu[row * 768 + d]);
    float wvv = f32 ? wf[d] : b2f(wu[d]);
    s += yv * wvv;
  }
#pragma unroll
  for (int o = 32; o > 0; o >>= 1) s += __shfl_down(s, o);
  if (lane == 0) {
    float bb = f32 ? ((const float*)bc)[0] : b2f(((const ushortT*)bc)[0]);
    float mk = f32 ? ((const float*)mask)[row] : b2f(((const ushortT*)mask)[row]);
    float sig = 1.f / (1.f + __expf(-(s + bb)));
    long oi = 6291456L + row;
    if (f32) ((float*)outbase)[oi] = sig * mk;
    else ((ushortT*)outbase)[oi] = f2b(sig * mk);
  }
}

extern "C" void kernel_launch(void* const* d_in, const int* in_sizes, int n_in,
                              void* d_out, int out_size, void* d_ws, size_t ws_size,
                              hipStream_t stream) {
  (void)in_sizes; (void)n_in; (void)out_size; (void)ws_size;

  const void* X    = d_in[0];               // [8,1024,768]
  const int*  adj  = (const int*)d_in[1];   // [8,1024,1024]
  const void* maskN= d_in[2];               // [8,1024]
  const void* Wh   = d_in[3];               // [4,768,768]
  const void* aH   = d_in[4];               // [4,1536]
  const void* Wo   = d_in[5];               // [3072,768]
  const void* aO   = d_in[6];               // [1536]
  const void* wcls = d_in[7];               // [768]
  const void* bcls = d_in[8];               // [1]

  char* ws = (char*)d_ws;
  float* Pws  = (float*)(ws + 0);           // f1 [1024] + f2 [1024]
  int*   flag = (int*)(ws + 8192);
  f16* Wh1T = (f16*)(ws + 8448);            // [768,1024] f16
  f16* Wh2T = (f16*)(ws + 1581312);         // [768,1024] f16
  f16* attb = (f16*)(ws + 3154176);         // [1024,1024] f16
  f16* hout = (f16*)(ws + 5251328);         // [1024,768] f16; end 6,824,192
  char* dob = (char*)d_out;

  detect_dtype<<<1, 256, 0, stream>>>((const ushortT*)X, flag, Pws, dob);

  auto mkG1 = [&](int b, int h) {
    GA g{}; g.A = X; g.B = Wh; g.C = Wh1T; g.R = nullptr; g.avec = aH;
    g.aOff = (long)b * 786432; g.bOff = (long)h * 589824;
    g.cOff = 0; g.rOff = 0; g.avOff = (long)h * 1536;
    g.K = 768; g.lda = 768; g.ldb = 768; g.aRaw = 1; g.accum = 0;
    g.fd = 1; g.fsel = (h + (b & 1)) & 1; g.zmask = 0;
    return g;
  };

  dim3 gg(12, 16), gp(12, 16, 2);
  k_solo<4, 1><<<gg, 256, 0, stream>>>(mkG1(0, 0), Pws, dob, flag);

  for (int b = 0; b < 8; b++) {
    int phase = b & 1;
    long xOff = (long)b * 786432;
    for (int h = 0; h < 4; h++) {
      // A1[h]
      attn_kernel<<<1024, 256, 0, stream>>>(
          Pws, dob, (h + phase) & 1, adj + (size_t)b * 1048576, attb, flag);
      // G2[h]: hout = elu(att @ Wh1); spare block zeroes next fdot target(s)
      GA g2{}; g2.A = attb; g2.B = Wh1T; g2.C = hout;
      g2.K = 1024; g2.lda = 1024; g2.ldb = 1024; g2.aRaw = 0; g2.accum = 0;
      g2.fd = 0; g2.fsel = 0;
      g2.zmask = (h < 3) ? (1 << ((h + 1 + phase) & 1)) : 3;
      k_solo<1, 0><<<gg, 256, 0, stream>>>(g2, Pws, dob, flag);
      // G3[h]: Wh2T (+)= (hout @ Wo_slice)^T
      GA g3{}; g3.A = hout; g3.B = Wo; g3.C = Wh2T; g3.avec = aO;
      g3.bOff = (long)h * 589824; g3.avOff = 0;
      g3.K = 768; g3.lda = 768; g3.ldb = 768; g3.aRaw = 0;
      g3.accum = h > 0 ? 1 : 0;
      g3.fd = (h == 3) ? 1 : 0; g3.fsel = phase; g3.zmask = 0;
      if (h < 3) {
        k_pair31<<<gp, 256, 0, stream>>>(g3, mkG1(b, h + 1), Pws, dob, flag);
      } else {
        k_solo<3, 1><<<gg, 256, 0, stream>>>(g3, Pws, dob, flag);
      }
    }
    // A2
    attn_kernel<<<1024, 256, 0, stream>>>(
        Pws, dob, phase, adj + (size_t)b * 1048576, attb, flag);
    // G4: yy[b] = elu(att2 @ Wh2) + X[b] -> d_out   (|| G1[0,b+1])
    GA g4{}; g4.A = attb; g4.B = Wh2T; g4.C = d_out; g4.R = X;
    g4.cOff = xOff; g4.rOff = xOff;
    g4.K = 1024; g4.lda = 1024; g4.ldb = 1024; g4.aRaw = 0; g4.accum = 0;
    g4.fd = 0; g4.fsel = 0; g4.zmask = 0;
    if (b < 7) {
      k_pair41<<<gp, 256, 0, stream>>>(g4, mkG1(b + 1, 0), Pws, dob, flag);
    } else {
      k_solo<2, 0><<<gg, 256, 0, stream>>>(g4, Pws, dob, flag);
    }
  }

  cls_kernel<<<2048, 256, 0, stream>>>(d_out, wcls, bcls, maskN, flag);
}